// Round 13
// baseline (302.163 us; speedup 1.0000x reference)
//
#include <hip/hip_runtime.h>
#include <hip/hip_bf16.h>
#include <math.h>

#define BB 1024
#define NSITES 512
#define NFF 64
#define KKK 4
#define WDD 64
#define CAP 256   // max samples per site

// ws layout (bytes)
#define OFF_R      0          // [BB][64] int       -> 262144
#define OFF_NF     262144     // [BB][64][2] f32    -> 786432
#define OFF_WLC    786432     // [K][64][64] float2 -> 917504
#define OFF_PT     917504     //                    -> 918528
#define OFF_C0     918528     //                    -> 919552
#define OFF_FEATP  919552     // [BB][K][4][64] f32 -> 5113856
#define OFF_LA     5113856    // [BB][K] f32        -> 5130240
#define OFF_SG     5130240    //                    -> 5146624
#define OFF_FEATC  5146624    // [BB][K][64] f32    -> 6195200
#define OFF_CNT    6195200    // [512] int          -> 6197248
#define OFF_LISTS  6197248    // [512][CAP] int     -> 6721536
#define OFF_ASTORE 6721536    // [BB][K][64][64] f32 -> 73830400
#define WS_NEED    73830400

// 32-point twiddle tables as compile-time constants (folded under full unroll)
constexpr float KC32[32] = {
  1.0f, 0.980785280f, 0.923879533f, 0.831469612f, 0.707106781f, 0.555570233f, 0.382683432f, 0.195090322f,
  0.0f,-0.195090322f,-0.382683432f,-0.555570233f,-0.707106781f,-0.831469612f,-0.923879533f,-0.980785280f,
 -1.0f,-0.980785280f,-0.923879533f,-0.831469612f,-0.707106781f,-0.555570233f,-0.382683432f,-0.195090322f,
  0.0f, 0.195090322f, 0.382683432f, 0.555570233f, 0.707106781f, 0.831469612f, 0.923879533f, 0.980785280f
};
constexpr float KS32[32] = {
  0.0f, 0.195090322f, 0.382683432f, 0.555570233f, 0.707106781f, 0.831469612f, 0.923879533f, 0.980785280f,
  1.0f, 0.980785280f, 0.923879533f, 0.831469612f, 0.707106781f, 0.555570233f, 0.382683432f, 0.195090322f,
  0.0f,-0.195090322f,-0.382683432f,-0.555570233f,-0.707106781f,-0.831469612f,-0.923879533f,-0.980785280f,
 -1.0f,-0.980785280f,-0.923879533f,-0.831469612f,-0.707106781f,-0.555570233f,-0.382683432f,-0.195090322f
};

// tanh-approx gelu: z * sigmoid(A(z+Bz^3)); exp2-folded (A'=A*log2e), rcp.
__device__ __forceinline__ float gelu_t(float z) {
  float z2 = z * z;
  float t  = fmaf(0.1029432f, z2, 2.3022082f);   // A*log2e*(1 + B z^2)
  float e  = __builtin_amdgcn_exp2f(-(z * t));
  return z * __builtin_amdgcn_rcpf(1.f + e);
}

// ---------------- K0: fold W_lift into spectral weights (4-wave); zero scnt --
__launch_bounds__(256)
__global__ void k0_prep(const float* __restrict__ Wl, const float* __restrict__ bl,
                        const float* __restrict__ Wre, const float* __restrict__ Wim,
                        const float* __restrict__ Wpt, const float* __restrict__ bpt,
                        float2* __restrict__ WLc,
                        float* __restrict__ PT, float* __restrict__ C0,
                        int* __restrict__ site_cnt) {
  int k = blockIdx.x >> 6, o = blockIdx.x & 63;
  int m = threadIdx.x & 63, iq = threadIdx.x >> 6;   // wave iq: i in [iq*16, iq*16+16)
  __shared__ float arS[4][64], aiS[4][64];
  __shared__ float ptS[4], c0S[4];
  if (blockIdx.x == 0) {
    site_cnt[threadIdx.x] = 0;
    site_cnt[threadIdx.x + 256] = 0;
  }
  float ar = 0.f, ai = 0.f;
  for (int i = iq*16; i < iq*16 + 16; ++i) {
    float L = Wl[k*WDD + i];
    int idx = ((k*WDD + i)*WDD + o)*64 + m;
    ar += L * Wre[idx];
    ai += L * Wim[idx];
  }
  arS[iq][m] = ar; aiS[iq][m] = ai;
  if (m == 0) {
    float pt = 0.f, c0 = 0.f;
    for (int i = iq*16; i < iq*16 + 16; ++i) {
      float L = Wl[k*WDD + i];
      float b = bl[k*WDD + i];
      float wpv = Wpt[(k*WDD + i)*WDD + o];
      pt += L * wpv;
      c0 += b * wpv;
      c0 += b * Wre[((k*WDD + i)*WDD + o)*64 + 0];
    }
    ptS[iq] = pt; c0S[iq] = c0;
  }
  __syncthreads();
  if (threadIdx.x < 64) {
    int t = threadIdx.x;
    WLc[(k*64 + t)*WDD + o] = make_float2(arS[0][t]+arS[1][t]+arS[2][t]+arS[3][t],
                                          aiS[0][t]+aiS[1][t]+aiS[2][t]+aiS[3][t]);
    if (t == 0) {
      PT[k*WDD + o] = ptS[0]+ptS[1]+ptS[2]+ptS[3];
      C0[k*WDD + o] = c0S[0]+c0S[1]+c0S[2]+c0S[3] + bpt[k*WDD + o];
    }
  }
}

// ---------------- K1: occupied list + inverse index --------------------------
__global__ void k1_occ(const int* __restrict__ n, int* __restrict__ R,
                       int* __restrict__ site_cnt, int* __restrict__ lists) {
  int b = blockIdx.x, s = threadIdx.x;
  __shared__ int cnts[8];
  int occ = n[b*NSITES + s] > 0;
  unsigned long long bal = __ballot(occ);
  int w = s >> 6, lane = s & 63;
  if (lane == 0) cnts[w] = __popcll(bal);
  __syncthreads();
  int base = 0;
  for (int i = 0; i < w; ++i) base += cnts[i];
  int rank = base + __popcll(bal & ((1ull << lane) - 1ull));
  if (occ) {
    R[b*NFF + rank] = s;
    int idx = atomicAdd(&site_cnt[s], 1);
    if (idx < CAP) lists[s*CAP + idx] = (b << 6) | rank;
  }
}

// ---------------- K2: Nf[b,x,y] = rfft2 corner; 4-way j-split ----------------
__global__ void k2_nf(const int* __restrict__ R, float* __restrict__ Nf) {
  int b = blockIdx.x, tid = threadIdx.x;         // 256 threads
  int m = tid & 63, jg = tid >> 6;               // mode, j-group
  __shared__ int Rs[NFF];
  __shared__ float cs[32], sn[32];
  __shared__ float2 part[4][64];
  if (tid < 64) Rs[tid] = R[b*NFF + tid];
  if (tid >= 64 && tid < 96) {
    int t = tid - 64;
    float a = 6.283185307179586f * (float)t / 32.f;
    sincosf(a, &sn[t], &cs[t]);
  }
  __syncthreads();
  int x = m >> 3, y = m & 7;
  float re = 0.f, im = 0.f;
  #pragma unroll
  for (int q = 0; q < 16; ++q) {
    int r = Rs[jg*16 + q];
    int mm = (2*(r >> 5)*x + (r & 31)*y) & 31;
    re += cs[mm]; im -= sn[mm];
  }
  part[jg][m] = make_float2(re, im);
  __syncthreads();
  if (tid < 64) {
    float2 a0 = part[0][tid], a1 = part[1][tid], a2 = part[2][tid], a3 = part[3][tid];
    Nf[(b*64 + tid)*2 + 0] = (a0.x + a1.x) + (a2.x + a3.x);
    Nf[(b*64 + tid)*2 + 1] = (a0.y + a1.y) + (a2.y + a3.y);
  }
}

// ---------------- K3: spectral field + gelu + partial site-sum ---------------
// grid (B, K, 4): blockIdx.z = h-quarter (h in [qq*4, qq*4+4)); ~19.6 KB LDS.
__launch_bounds__(256)
__global__ void k3_field(const int* __restrict__ n, const float* __restrict__ Nf,
                         const float2* __restrict__ WLc,
                         const float* __restrict__ PT, const float* __restrict__ C0,
                         float* __restrict__ featP) {
  int b = blockIdx.x, k = blockIdx.y, qq = blockIdx.z;
  int tid = threadIdx.x;
  __shared__ float2 g2[4][8][64];                        // [hl][y][o]  16 KB
  __shared__ __align__(16) float2 TNc[4][8][8];          // [hl][y][x]   2 KB
  __shared__ float c16[16], s16[16];
  __shared__ float NfS[64][2];
  __shared__ unsigned nmask[4];                          // occupancy bits per hl
  __shared__ float featS[4][64];

  if (tid < 16) sincosf(6.283185307179586f*(float)tid/16.f, &s16[tid], &c16[tid]);
  if (tid >= 64 && tid < 128) { int t2 = tid-64; NfS[t2][0] = Nf[(b*64+t2)*2]; NfS[t2][1] = Nf[(b*64+t2)*2+1]; }
  if (tid < 128) {
    int occ = n[b*NSITES + qq*128 + tid] > 0;
    unsigned long long bal = __ballot(occ);
    if ((tid & 63) == 0) {
      int wv = tid >> 6;
      nmask[wv*2 + 0] = (unsigned)(bal & 0xffffffffull);
      nmask[wv*2 + 1] = (unsigned)(bal >> 32);
    }
  }
  __syncthreads();

  // TN[hl,y,x] = e^{+2pi i h_g x/16} * Nf[x,y],  h_g = qq*4 + hl  (one pass)
  {
    int hl = tid >> 6, y = (tid >> 3) & 7, x = tid & 7;
    int hg = qq*4 + hl;
    int m = (hg*x) & 15;
    float twr = c16[m], twi = s16[m];
    float nr = NfS[x*8+y][0], ni = NfS[x*8+y][1];
    TNc[hl][y][x] = make_float2(twr*nr - twi*ni, twr*ni + twi*nr);
  }
  __syncthreads();

  int o = tid & 63, grp = tid >> 6;
  // phase B: g[hl,y,o] = (a_y/512) * sum_x TN[hl,y,x] * WL[x,y,o]
  for (int y = grp; y < 8; y += 4) {
    float2 wl[8];
    #pragma unroll
    for (int x = 0; x < 8; ++x) wl[x] = WLc[(k*64 + x*8 + y)*64 + o];
    float sc = (y == 0) ? (1.f/512.f) : (2.f/512.f);
    #pragma unroll
    for (int hl = 0; hl < 4; ++hl) {
      float gr = 0.f, gi = 0.f;
      const float4* trow = reinterpret_cast<const float4*>(&TNc[hl][y][0]);
      #pragma unroll
      for (int xp = 0; xp < 4; ++xp) {
        float4 tp = trow[xp];
        float2 w0 = wl[2*xp], w1 = wl[2*xp+1];
        gr += tp.x*w0.x - tp.y*w0.y;
        gi += tp.x*w0.y + tp.y*w0.x;
        gr += tp.z*w1.x - tp.w*w1.y;
        gi += tp.z*w1.y + tp.w*w1.x;
      }
      g2[hl][y][o] = make_float2(gr * sc, gi * sc);
    }
  }
  __syncthreads();

  // phase C: one hl per wave-group; quadrant symmetry {w, 32-w, 16+w, 16-w}
  float PTo = PT[k*WDD + o], C0o = C0[k*WDD + o];
  float c0p = C0o + PTo;
  float accf = 0.f;
#define ZS(W, V) { float zz = (((msk >> (W)) & 1u) ? c0p : C0o) + (V); accf += gelu_t(zz); }
  {
    float2 gv[8];
    #pragma unroll
    for (int y = 0; y < 8; ++y) gv[y] = g2[grp][y][o];
    unsigned msk = (unsigned)__builtin_amdgcn_readfirstlane((int)nmask[grp]);
    {
      float v = ((gv[0].x+gv[1].x)+(gv[2].x+gv[3].x))+((gv[4].x+gv[5].x)+(gv[6].x+gv[7].x));
      ZS(0, v);
    }
    {
      float v = ((gv[0].x-gv[1].x)+(gv[2].x-gv[3].x))+((gv[4].x-gv[5].x)+(gv[6].x-gv[7].x));
      ZS(16, v);
    }
    {
      float cE = (gv[0].x - gv[2].x) + (gv[4].x - gv[6].x);
      float sO = (gv[1].y - gv[3].y) + (gv[5].y - gv[7].y);
      ZS(8,  cE - sO);
      ZS(24, cE + sO);
    }
    #pragma unroll
    for (int w = 1; w < 8; ++w) {
      float cE = gv[0].x, cO = 0.f, sE = 0.f, sO = 0.f;
      #pragma unroll
      for (int y = 2; y < 8; y += 2) {
        const int m = (w*y) & 31;
        if (KC32[m] != 0.f) cE = fmaf(gv[y].x, KC32[m], cE);
        if (KS32[m] != 0.f) sE = fmaf(gv[y].y, KS32[m], sE);
      }
      #pragma unroll
      for (int y = 1; y < 8; y += 2) {
        const int m = (w*y) & 31;
        if (KC32[m] != 0.f) cO = fmaf(gv[y].x, KC32[m], cO);
        if (KS32[m] != 0.f) sO = fmaf(gv[y].y, KS32[m], sO);
      }
      float CA = cE + cO, CB = cE - cO, SA = sE + sO, SB = sE - sO;
      ZS(w,      CA - SA);
      ZS(32 - w, CA + SA);
      ZS(16 + w, CB - SB);
      ZS(16 - w, CB + SB);
    }
  }
#undef ZS
  featS[grp][o] = accf;
  __syncthreads();
  if (tid < 64) {
    featP[((b*KKK + k)*4 + qq)*64 + tid] =
      featS[0][tid]+featS[1][tid]+featS[2][tid]+featS[3][tid];
  }
}

// ---------------- KF: combine feat quarters ----------------------------------
__global__ void kf_comb(const float* __restrict__ featP, float* __restrict__ featC) {
  int b = blockIdx.x, tid = threadIdx.x;       // tid = k*64+o
  int base = b*1024 + (tid >> 6)*256 + (tid & 63);
  featC[b*256 + tid] = (featP[base] + featP[base + 64] + featP[base + 128] + featP[base + 192])
                       * (1.f/512.f);
}

// ---------------- K4a: panel in regs; LDS-staged list; 2-row pipeline --------
__launch_bounds__(256)
__global__ void k4a_proj(const float* __restrict__ featC, const int* __restrict__ site_cnt,
                         const int* __restrict__ lists, const float* __restrict__ Wproj,
                         const float* __restrict__ bproj, float* __restrict__ Astore) {
  int s = blockIdx.x, k = blockIdx.y;
  int lane = threadIdx.x & 63, wave = threadIdx.x >> 6;
  __shared__ int listS[CAP];
  int cnt = site_cnt[s];
  if (cnt > CAP) cnt = CAP;
  for (int i = threadIdx.x; i < cnt; i += 256) listS[i] = lists[s*CAP + i];
  float preg[64];
  const float* wp = Wproj + (size_t)(k*64)*32768 + s*64 + lane;
  #pragma unroll
  for (int o = 0; o < 64; ++o) preg[o] = wp[(size_t)o * 32768];
  float biasj = bproj[k*32768 + s*64 + lane];
  __syncthreads();
  // wave w handles i = w, w+4 pairs stepping by 8: residues {w, w+4} mod 8 — disjoint, full cover
  for (int i = wave; i < cnt; i += 8) {
    int p0 = __builtin_amdgcn_readfirstlane(listS[i]);
    int i1 = i + 4;
    bool has1 = i1 < cnt;
    int p1 = has1 ? __builtin_amdgcn_readfirstlane(listS[i1]) : p0;
    const float* f0 = featC + (size_t)((p0 >> 6)*KKK + k)*64;   // uniform -> s_loads
    const float* f1 = featC + (size_t)((p1 >> 6)*KKK + k)*64;
    float a0 = biasj, a1 = biasj;
    #pragma unroll
    for (int o = 0; o < 64; ++o) {
      a0 = fmaf(f0[o], preg[o], a0);
      a1 = fmaf(f1[o], preg[o], a1);
    }
    Astore[(((size_t)(p0 >> 6)*KKK + k)*64 + (p0 & 63))*64 + lane] = a0;
    if (has1)
      Astore[(((size_t)(p1 >> 6)*KKK + k)*64 + (p1 & 63))*64 + lane] = a1;
  }
}

// ---------------- K4b: register LU (mantissa-product log) + fused output -----
__launch_bounds__(256)
__global__ void k4b_lu(const float* __restrict__ Astore, const float* __restrict__ lc,
                       float* __restrict__ out, int out_size) {
  int b = blockIdx.x;
  int k = threadIdx.x >> 6, lane = threadIdx.x & 63;
  __shared__ float laS[4], sgS[4];
  const float* Ab = Astore + (((size_t)b*KKK + k) << 12);
  float col[64];
  #pragma unroll
  for (int j4 = 0; j4 < 64; j4 += 4) {
    float4 v = *reinterpret_cast<const float4*>(Ab + lane*64 + j4);
    col[j4] = v.x; col[j4+1] = v.y; col[j4+2] = v.z; col[j4+3] = v.w;
  }
  float psum = 1.f;       // product of pivot mantissas in [1,2); <= 2^64 fits f32
  int   esum = 0;         // sum of pivot exponents
  int signflips = 0;
  int pvec = 0;
  bool elim = false;
  #pragma unroll
  for (int s = 0; s < 64; ++s) {
    unsigned key = elim ? (unsigned)lane
                        : ((__float_as_uint(fabsf(col[s])) & 0xFFFFFFC0u) | (unsigned)lane);
    #pragma unroll
    for (int m = 1; m < 64; m <<= 1) {
      unsigned ok = (unsigned)__shfl_xor((int)key, m, 64);
      key = (ok > key) ? ok : key;
    }
    int piv = __builtin_amdgcn_readfirstlane((int)(key & 63u));   // SGPR
    float d = __int_as_float(__builtin_amdgcn_readlane(__float_as_int(col[s]), piv));
    if (lane == s) pvec = piv;
    bool isPiv = (lane == piv);
    unsigned db = __float_as_uint(fabsf(d));
    if (db == 0u) psum = 0.f;                              // -> logf(0) = -inf
    esum += (int)((db >> 23) & 0xFFu) - 127;
    psum *= __uint_as_float((db & 0x007FFFFFu) | 0x3F800000u);
    signflips += (d < 0.f) ? 1 : 0;
    float rd = __builtin_amdgcn_rcpf(d);
    float f = (elim || isPiv || d == 0.f) ? 0.f : col[s] * rd;
    if (isPiv) elim = true;
    #pragma unroll
    for (int j = s + 1; j < 64; ++j) {
      float uj = __int_as_float(__builtin_amdgcn_readlane(__float_as_int(col[j]), piv));
      col[j] = fmaf(-f, uj, col[j]);
    }
  }
  float logacc = logf(psum) + (float)esum * 0.6931471805599453f;
  int inv = 0;
  #pragma unroll
  for (int dd = 1; dd < 64; ++dd) {
    int other = __shfl_down(pvec, dd, 64);
    unsigned long long mm = __ballot((lane + dd < 64) && (pvec > other));
    if (lane == 0) inv += __popcll(mm);
  }
  if (lane == 0) {
    laS[k] = logacc;
    sgS[k] = (((inv + signflips) & 1)) ? -1.f : 1.f;
  }
  __syncthreads();
  if (threadIdx.x == 0) {
    float t0 = laS[0] + lc[0], t1 = laS[1] + lc[1];
    float t2 = laS[2] + lc[2], t3 = laS[3] + lc[3];
    float m = fmaxf(fmaxf(t0, t1), fmaxf(t2, t3));
    float S = sgS[0]*expf(t0-m) + sgS[1]*expf(t1-m) + sgS[2]*expf(t2-m) + sgS[3]*expf(t3-m);
    float re = logf(fabsf(S)) + m;
    float im = (S < 0.f) ? -3.14159265358979f : 0.f;   // planar [re|im]
    if (b      < out_size) out[b]      = re;
    if (BB + b < out_size) out[BB + b] = im;
  }
}

// ---------------- K4 fallback: monolithic (if ws too small) ------------------
__launch_bounds__(256)
__global__ void k4_det(const float* __restrict__ featP, const int* __restrict__ R,
                       const float* __restrict__ Wproj, const float* __restrict__ bproj,
                       float* __restrict__ la, float* __restrict__ sg) {
  int b = blockIdx.x, k = blockIdx.y;
  int tid = threadIdx.x;
  __shared__ float A[64][65];
  __shared__ float fL[64];
  __shared__ int Rl[64];
  if (tid < 64) {
    int base = (b*KKK + k)*256;
    fL[tid] = (featP[base + tid] + featP[base + 64 + tid] +
               featP[base + 128 + tid] + featP[base + 192 + tid]) * (1.f/512.f);
    Rl[tid] = R[b*NFF + tid];
  }
  __syncthreads();
  int j = tid & 63, ig = tid >> 6;
  for (int i = ig; i < 64; i += 4) {
    int col = Rl[i]*NFF + j;
    float acc = bproj[k*(NSITES*NFF) + col];
    const float* wp = Wproj + (size_t)(k*WDD)*32768 + col;
    #pragma unroll 4
    for (int o = 0; o < 64; ++o) acc += fL[o] * wp[(size_t)o * 32768];
    A[i][j] = acc;
  }
  __syncthreads();
  int t = tid & 63;
  int parity = 0;
  for (int s = 0; s < 64; ++s) {
    float v = (t >= s) ? fabsf(A[t][s]) : -1.f;
    int idx = t;
    #pragma unroll
    for (int m = 1; m < 64; m <<= 1) {
      float ov = __shfl_xor(v, m, 64);
      int oi = __shfl_xor(idx, m, 64);
      if (ov > v || (ov == v && oi < idx)) { v = ov; idx = oi; }
    }
    int piv = idx;
    __syncthreads();
    if (piv != s) {
      if (t < 16) {
        int j2 = ig*16 + t;
        float tmp = A[s][j2]; A[s][j2] = A[piv][j2]; A[piv][j2] = tmp;
      }
      parity ^= 1;
    }
    __syncthreads();
    float d = A[s][s];
    if (d != 0.f && t > s) {
      float f = A[t][s] / d;
      #pragma unroll
      for (int jj = 0; jj < 16; ++jj) {
        int j2 = ig*16 + jj;
        if (j2 > s) A[t][j2] -= f * A[s][j2];
      }
    }
    __syncthreads();
  }
  if (ig == 0) {
    float d = A[t][t];
    float l = logf(fabsf(d));
    #pragma unroll
    for (int m = 1; m < 64; m <<= 1) l += __shfl_xor(l, m, 64);
    unsigned long long neg = __ballot(d < 0.f);
    if (t == 0) {
      la[b*KKK + k] = l;
      int p = ((int)__popcll(neg) + parity) & 1;
      sg[b*KKK + k] = p ? -1.f : 1.f;
    }
  }
}

// ---------------- K5: signed complex logsumexp (fallback path only) ----------
__global__ void k5_out(const float* __restrict__ la, const float* __restrict__ sg,
                       const float* __restrict__ lc, float* __restrict__ out, int out_size) {
  int b = blockIdx.x * blockDim.x + threadIdx.x;
  if (b >= BB) return;
  float t0 = la[b*KKK+0] + lc[0];
  float t1 = la[b*KKK+1] + lc[1];
  float t2 = la[b*KKK+2] + lc[2];
  float t3 = la[b*KKK+3] + lc[3];
  float m = fmaxf(fmaxf(t0, t1), fmaxf(t2, t3));
  float S = sg[b*KKK+0]*expf(t0-m) + sg[b*KKK+1]*expf(t1-m)
          + sg[b*KKK+2]*expf(t2-m) + sg[b*KKK+3]*expf(t3-m);
  float re = logf(fabsf(S)) + m;
  float im = (S < 0.f) ? -3.14159265358979f : 0.f;
  if (b      < out_size) out[b]      = re;
  if (BB + b < out_size) out[BB + b] = im;
}

extern "C" void kernel_launch(void* const* d_in, const int* in_sizes, int n_in,
                              void* d_out, int out_size, void* d_ws, size_t ws_size,
                              hipStream_t stream) {
  const int*   n        = (const int*)  d_in[0];
  const float* W_lift   = (const float*)d_in[1];
  const float* b_lift   = (const float*)d_in[2];
  const float* Wsp_re   = (const float*)d_in[3];
  const float* Wsp_im   = (const float*)d_in[4];
  const float* W_pt     = (const float*)d_in[5];
  const float* b_pt     = (const float*)d_in[6];
  const float* W_proj   = (const float*)d_in[7];
  const float* b_proj   = (const float*)d_in[8];
  const float* log_c    = (const float*)d_in[9];

  char* ws = (char*)d_ws;
  int*   R      = (int*)  (ws + OFF_R);
  float* Nf     = (float*)(ws + OFF_NF);
  float2* WLc   = (float2*)(ws + OFF_WLC);
  float* PT     = (float*)(ws + OFF_PT);
  float* C0     = (float*)(ws + OFF_C0);
  float* featP  = (float*)(ws + OFF_FEATP);
  float* la     = (float*)(ws + OFF_LA);
  float* sg     = (float*)(ws + OFF_SG);
  float* featC  = (float*)(ws + OFF_FEATC);
  int*   scnt   = (int*)  (ws + OFF_CNT);
  int*   lists  = (int*)  (ws + OFF_LISTS);
  float* Astore = (float*)(ws + OFF_ASTORE);

  k0_prep<<<dim3(256), dim3(256), 0, stream>>>(W_lift, b_lift, Wsp_re, Wsp_im, W_pt, b_pt,
                                               WLc, PT, C0, scnt);
  k1_occ<<<dim3(BB), dim3(NSITES), 0, stream>>>(n, R, scnt, lists);
  k2_nf<<<dim3(BB), dim3(256), 0, stream>>>(R, Nf);
  k3_field<<<dim3(BB, KKK, 4), dim3(256), 0, stream>>>(n, Nf, WLc, PT, C0, featP);
  if (ws_size >= (size_t)WS_NEED) {
    kf_comb<<<dim3(BB), dim3(256), 0, stream>>>(featP, featC);
    k4a_proj<<<dim3(NSITES, KKK), dim3(256), 0, stream>>>(featC, scnt, lists, W_proj, b_proj, Astore);
    k4b_lu<<<dim3(BB), dim3(256), 0, stream>>>(Astore, log_c, (float*)d_out, out_size);
  } else {
    k4_det<<<dim3(BB, KKK), dim3(256), 0, stream>>>(featP, R, W_proj, b_proj, la, sg);
    k5_out<<<dim3(4), dim3(256), 0, stream>>>(la, sg, log_c, (float*)d_out, out_size);
  }
}

// Round 14
// 264.501 us; speedup vs baseline: 1.1424x; 1.1424x over previous
//
#include <hip/hip_runtime.h>
#include <hip/hip_bf16.h>
#include <math.h>

#define BB 1024
#define NSITES 512
#define NFF 64
#define KKK 4
#define WDD 64
#define CAP 256   // max samples per site

// ws layout (bytes)
#define OFF_R      0          // [BB][64] int       -> 262144
#define OFF_NF     262144     // [BB][64][2] f32    -> 786432
#define OFF_WLC    786432     // [K][64][64] float2 -> 917504
#define OFF_PT     917504     //                    -> 918528
#define OFF_C0     918528     //                    -> 919552
#define OFF_FEATP  919552     // [BB][K][4][64] f32 -> 5113856
#define OFF_LA     5113856    // [BB][K] f32        -> 5130240
#define OFF_SG     5130240    //                    -> 5146624
#define OFF_FEATC  5146624    // [BB][K][64] f32    -> 6195200
#define OFF_CNT    6195200    // [512] int          -> 6197248
#define OFF_LISTS  6197248    // [512][CAP] int     -> 6721536
#define OFF_ASTORE 6721536    // [BB][K][64][64] f32 -> 73830400
#define WS_NEED    73830400

// 32-point twiddle tables as compile-time constants (folded under full unroll)
constexpr float KC32[32] = {
  1.0f, 0.980785280f, 0.923879533f, 0.831469612f, 0.707106781f, 0.555570233f, 0.382683432f, 0.195090322f,
  0.0f,-0.195090322f,-0.382683432f,-0.555570233f,-0.707106781f,-0.831469612f,-0.923879533f,-0.980785280f,
 -1.0f,-0.980785280f,-0.923879533f,-0.831469612f,-0.707106781f,-0.555570233f,-0.382683432f,-0.195090322f,
  0.0f, 0.195090322f, 0.382683432f, 0.555570233f, 0.707106781f, 0.831469612f, 0.923879533f, 0.980785280f
};
constexpr float KS32[32] = {
  0.0f, 0.195090322f, 0.382683432f, 0.555570233f, 0.707106781f, 0.831469612f, 0.923879533f, 0.980785280f,
  1.0f, 0.980785280f, 0.923879533f, 0.831469612f, 0.707106781f, 0.555570233f, 0.382683432f, 0.195090322f,
  0.0f,-0.195090322f,-0.382683432f,-0.555570233f,-0.707106781f,-0.831469612f,-0.923879533f,-0.980785280f,
 -1.0f,-0.980785280f,-0.923879533f,-0.831469612f,-0.707106781f,-0.555570233f,-0.382683432f,-0.195090322f
};

// tanh-approx gelu: z * sigmoid(A(z+Bz^3)); exp2-folded (A'=A*log2e), rcp.
__device__ __forceinline__ float gelu_t(float z) {
  float z2 = z * z;
  float t  = fmaf(0.1029432f, z2, 2.3022082f);   // A*log2e*(1 + B z^2)
  float e  = __builtin_amdgcn_exp2f(-(z * t));
  return z * __builtin_amdgcn_rcpf(1.f + e);
}

// ---------------- K0: fold W_lift into spectral weights (4-wave); zero scnt --
__launch_bounds__(256)
__global__ void k0_prep(const float* __restrict__ Wl, const float* __restrict__ bl,
                        const float* __restrict__ Wre, const float* __restrict__ Wim,
                        const float* __restrict__ Wpt, const float* __restrict__ bpt,
                        float2* __restrict__ WLc,
                        float* __restrict__ PT, float* __restrict__ C0,
                        int* __restrict__ site_cnt) {
  int k = blockIdx.x >> 6, o = blockIdx.x & 63;
  int m = threadIdx.x & 63, iq = threadIdx.x >> 6;   // wave iq: i in [iq*16, iq*16+16)
  __shared__ float arS[4][64], aiS[4][64];
  __shared__ float ptS[4], c0S[4];
  if (blockIdx.x == 0) {
    site_cnt[threadIdx.x] = 0;
    site_cnt[threadIdx.x + 256] = 0;
  }
  float ar = 0.f, ai = 0.f;
  for (int i = iq*16; i < iq*16 + 16; ++i) {
    float L = Wl[k*WDD + i];
    int idx = ((k*WDD + i)*WDD + o)*64 + m;
    ar += L * Wre[idx];
    ai += L * Wim[idx];
  }
  arS[iq][m] = ar; aiS[iq][m] = ai;
  if (m == 0) {
    float pt = 0.f, c0 = 0.f;
    for (int i = iq*16; i < iq*16 + 16; ++i) {
      float L = Wl[k*WDD + i];
      float b = bl[k*WDD + i];
      float wpv = Wpt[(k*WDD + i)*WDD + o];
      pt += L * wpv;
      c0 += b * wpv;
      c0 += b * Wre[((k*WDD + i)*WDD + o)*64 + 0];
    }
    ptS[iq] = pt; c0S[iq] = c0;
  }
  __syncthreads();
  if (threadIdx.x < 64) {
    int t = threadIdx.x;
    WLc[(k*64 + t)*WDD + o] = make_float2(arS[0][t]+arS[1][t]+arS[2][t]+arS[3][t],
                                          aiS[0][t]+aiS[1][t]+aiS[2][t]+aiS[3][t]);
    if (t == 0) {
      PT[k*WDD + o] = ptS[0]+ptS[1]+ptS[2]+ptS[3];
      C0[k*WDD + o] = c0S[0]+c0S[1]+c0S[2]+c0S[3] + bpt[k*WDD + o];
    }
  }
}

// ---------------- K1: occupied list + inverse index --------------------------
__global__ void k1_occ(const int* __restrict__ n, int* __restrict__ R,
                       int* __restrict__ site_cnt, int* __restrict__ lists) {
  int b = blockIdx.x, s = threadIdx.x;
  __shared__ int cnts[8];
  int occ = n[b*NSITES + s] > 0;
  unsigned long long bal = __ballot(occ);
  int w = s >> 6, lane = s & 63;
  if (lane == 0) cnts[w] = __popcll(bal);
  __syncthreads();
  int base = 0;
  for (int i = 0; i < w; ++i) base += cnts[i];
  int rank = base + __popcll(bal & ((1ull << lane) - 1ull));
  if (occ) {
    R[b*NFF + rank] = s;
    int idx = atomicAdd(&site_cnt[s], 1);
    if (idx < CAP) lists[s*CAP + idx] = (b << 6) | rank;
  }
}

// ---------------- K2: Nf[b,x,y] = rfft2 corner; 4-way j-split ----------------
__global__ void k2_nf(const int* __restrict__ R, float* __restrict__ Nf) {
  int b = blockIdx.x, tid = threadIdx.x;         // 256 threads
  int m = tid & 63, jg = tid >> 6;               // mode, j-group
  __shared__ int Rs[NFF];
  __shared__ float cs[32], sn[32];
  __shared__ float2 part[4][64];
  if (tid < 64) Rs[tid] = R[b*NFF + tid];
  if (tid >= 64 && tid < 96) {
    int t = tid - 64;
    float a = 6.283185307179586f * (float)t / 32.f;
    sincosf(a, &sn[t], &cs[t]);
  }
  __syncthreads();
  int x = m >> 3, y = m & 7;
  float re = 0.f, im = 0.f;
  #pragma unroll
  for (int q = 0; q < 16; ++q) {
    int r = Rs[jg*16 + q];
    int mm = (2*(r >> 5)*x + (r & 31)*y) & 31;
    re += cs[mm]; im -= sn[mm];
  }
  part[jg][m] = make_float2(re, im);
  __syncthreads();
  if (tid < 64) {
    float2 a0 = part[0][tid], a1 = part[1][tid], a2 = part[2][tid], a3 = part[3][tid];
    Nf[(b*64 + tid)*2 + 0] = (a0.x + a1.x) + (a2.x + a3.x);
    Nf[(b*64 + tid)*2 + 1] = (a0.y + a1.y) + (a2.y + a3.y);
  }
}

// ---------------- K3: spectral field + gelu + partial site-sum ---------------
// grid (B, K, 4): blockIdx.z = h-quarter. (256,4) -> 64-VGPR budget so the
// 8 gv modes + quadrant temps stay in registers (24-VGPR build re-read LDS).
__launch_bounds__(256, 4)
__global__ void k3_field(const int* __restrict__ n, const float* __restrict__ Nf,
                         const float2* __restrict__ WLc,
                         const float* __restrict__ PT, const float* __restrict__ C0,
                         float* __restrict__ featP) {
  int b = blockIdx.x, k = blockIdx.y, qq = blockIdx.z;
  int tid = threadIdx.x;
  __shared__ float2 g2[4][8][64];                        // [hl][y][o]  16 KB
  __shared__ __align__(16) float2 TNc[4][8][8];          // [hl][y][x]   2 KB
  __shared__ float c16[16], s16[16];
  __shared__ float NfS[64][2];
  __shared__ unsigned nmask[4];                          // occupancy bits per hl
  __shared__ float featS[4][64];

  if (tid < 16) sincosf(6.283185307179586f*(float)tid/16.f, &s16[tid], &c16[tid]);
  if (tid >= 64 && tid < 128) { int t2 = tid-64; NfS[t2][0] = Nf[(b*64+t2)*2]; NfS[t2][1] = Nf[(b*64+t2)*2+1]; }
  if (tid < 128) {
    int occ = n[b*NSITES + qq*128 + tid] > 0;
    unsigned long long bal = __ballot(occ);
    if ((tid & 63) == 0) {
      int wv = tid >> 6;
      nmask[wv*2 + 0] = (unsigned)(bal & 0xffffffffull);
      nmask[wv*2 + 1] = (unsigned)(bal >> 32);
    }
  }
  __syncthreads();

  // TN[hl,y,x] = e^{+2pi i h_g x/16} * Nf[x,y],  h_g = qq*4 + hl  (one pass)
  {
    int hl = tid >> 6, y = (tid >> 3) & 7, x = tid & 7;
    int hg = qq*4 + hl;
    int m = (hg*x) & 15;
    float twr = c16[m], twi = s16[m];
    float nr = NfS[x*8+y][0], ni = NfS[x*8+y][1];
    TNc[hl][y][x] = make_float2(twr*nr - twi*ni, twr*ni + twi*nr);
  }
  __syncthreads();

  int o = tid & 63, grp = tid >> 6;
  // phase B: g[hl,y,o] = (a_y/512) * sum_x TN[hl,y,x] * WL[x,y,o]
  for (int y = grp; y < 8; y += 4) {
    float2 wl[8];
    #pragma unroll
    for (int x = 0; x < 8; ++x) wl[x] = WLc[(k*64 + x*8 + y)*64 + o];
    float sc = (y == 0) ? (1.f/512.f) : (2.f/512.f);
    #pragma unroll
    for (int hl = 0; hl < 4; ++hl) {
      float gr = 0.f, gi = 0.f;
      const float4* trow = reinterpret_cast<const float4*>(&TNc[hl][y][0]);
      #pragma unroll
      for (int xp = 0; xp < 4; ++xp) {
        float4 tp = trow[xp];
        float2 w0 = wl[2*xp], w1 = wl[2*xp+1];
        gr += tp.x*w0.x - tp.y*w0.y;
        gi += tp.x*w0.y + tp.y*w0.x;
        gr += tp.z*w1.x - tp.w*w1.y;
        gi += tp.z*w1.y + tp.w*w1.x;
      }
      g2[hl][y][o] = make_float2(gr * sc, gi * sc);
    }
  }
  __syncthreads();

  // phase C: one hl per wave-group; quadrant symmetry {w, 32-w, 16+w, 16-w}
  float PTo = PT[k*WDD + o], C0o = C0[k*WDD + o];
  float c0p = C0o + PTo;
  float accf = 0.f;
#define ZS(W, V) { float zz = (((msk >> (W)) & 1u) ? c0p : C0o) + (V); accf += gelu_t(zz); }
  {
    float2 gv[8];
    #pragma unroll
    for (int y = 0; y < 8; ++y) gv[y] = g2[grp][y][o];
    unsigned msk = (unsigned)__builtin_amdgcn_readfirstlane((int)nmask[grp]);
    {
      float v = ((gv[0].x+gv[1].x)+(gv[2].x+gv[3].x))+((gv[4].x+gv[5].x)+(gv[6].x+gv[7].x));
      ZS(0, v);
    }
    {
      float v = ((gv[0].x-gv[1].x)+(gv[2].x-gv[3].x))+((gv[4].x-gv[5].x)+(gv[6].x-gv[7].x));
      ZS(16, v);
    }
    {
      float cE = (gv[0].x - gv[2].x) + (gv[4].x - gv[6].x);
      float sO = (gv[1].y - gv[3].y) + (gv[5].y - gv[7].y);
      ZS(8,  cE - sO);
      ZS(24, cE + sO);
    }
    #pragma unroll
    for (int w = 1; w < 8; ++w) {
      float cE = gv[0].x, cO = 0.f, sE = 0.f, sO = 0.f;
      #pragma unroll
      for (int y = 2; y < 8; y += 2) {
        const int m = (w*y) & 31;
        if (KC32[m] != 0.f) cE = fmaf(gv[y].x, KC32[m], cE);
        if (KS32[m] != 0.f) sE = fmaf(gv[y].y, KS32[m], sE);
      }
      #pragma unroll
      for (int y = 1; y < 8; y += 2) {
        const int m = (w*y) & 31;
        if (KC32[m] != 0.f) cO = fmaf(gv[y].x, KC32[m], cO);
        if (KS32[m] != 0.f) sO = fmaf(gv[y].y, KS32[m], sO);
      }
      float CA = cE + cO, CB = cE - cO, SA = sE + sO, SB = sE - sO;
      ZS(w,      CA - SA);
      ZS(32 - w, CA + SA);
      ZS(16 + w, CB - SB);
      ZS(16 - w, CB + SB);
    }
  }
#undef ZS
  featS[grp][o] = accf;
  __syncthreads();
  if (tid < 64) {
    featP[((b*KKK + k)*4 + qq)*64 + tid] =
      featS[0][tid]+featS[1][tid]+featS[2][tid]+featS[3][tid];
  }
}

// ---------------- KF: combine feat quarters ----------------------------------
__global__ void kf_comb(const float* __restrict__ featP, float* __restrict__ featC) {
  int b = blockIdx.x, tid = threadIdx.x;       // tid = k*64+o
  int base = b*1024 + (tid >> 6)*256 + (tid & 63);
  featC[b*256 + tid] = (featP[base] + featP[base + 64] + featP[base + 128] + featP[base + 192])
                       * (1.f/512.f);
}

// ---------------- K4a: panel in regs; LDS-staged list; single-row ------------
__launch_bounds__(256)
__global__ void k4a_proj(const float* __restrict__ featC, const int* __restrict__ site_cnt,
                         const int* __restrict__ lists, const float* __restrict__ Wproj,
                         const float* __restrict__ bproj, float* __restrict__ Astore) {
  int s = blockIdx.x, k = blockIdx.y;
  int lane = threadIdx.x & 63, wave = threadIdx.x >> 6;
  __shared__ int listS[CAP];
  int cnt = site_cnt[s];
  if (cnt > CAP) cnt = CAP;
  for (int i = threadIdx.x; i < cnt; i += 256) listS[i] = lists[s*CAP + i];
  float preg[64];
  const float* wp = Wproj + (size_t)(k*64)*32768 + s*64 + lane;
  #pragma unroll
  for (int o = 0; o < 64; ++o) preg[o] = wp[(size_t)o * 32768];
  float biasj = bproj[k*32768 + s*64 + lane];
  __syncthreads();
  for (int i = wave; i < cnt; i += 4) {
    int packed = __builtin_amdgcn_readfirstlane(listS[i]);
    int b = packed >> 6, rank = packed & 63;
    const float* fb = featC + ((size_t)b*KKK + k)*64;   // uniform -> s_loads
    float acc = biasj;
    #pragma unroll
    for (int o = 0; o < 64; ++o) acc = fmaf(fb[o], preg[o], acc);
    Astore[(((size_t)b*KKK + k)*64 + rank)*64 + lane] = acc;
  }
}

// ---------------- K4b: register LU (mantissa-product log) + fused output -----
__launch_bounds__(256)
__global__ void k4b_lu(const float* __restrict__ Astore, const float* __restrict__ lc,
                       float* __restrict__ out, int out_size) {
  int b = blockIdx.x;
  int k = threadIdx.x >> 6, lane = threadIdx.x & 63;
  __shared__ float laS[4], sgS[4];
  const float* Ab = Astore + (((size_t)b*KKK + k) << 12);
  float col[64];
  #pragma unroll
  for (int j4 = 0; j4 < 64; j4 += 4) {
    float4 v = *reinterpret_cast<const float4*>(Ab + lane*64 + j4);
    col[j4] = v.x; col[j4+1] = v.y; col[j4+2] = v.z; col[j4+3] = v.w;
  }
  float psum = 1.f;       // product of pivot mantissas in [1,2); <= 2^64 fits f32
  int   esum = 0;         // sum of pivot exponents
  int signflips = 0;
  int pvec = 0;
  bool elim = false;
  #pragma unroll
  for (int s = 0; s < 64; ++s) {
    unsigned key = elim ? (unsigned)lane
                        : ((__float_as_uint(fabsf(col[s])) & 0xFFFFFFC0u) | (unsigned)lane);
    #pragma unroll
    for (int m = 1; m < 64; m <<= 1) {
      unsigned ok = (unsigned)__shfl_xor((int)key, m, 64);
      key = (ok > key) ? ok : key;
    }
    int piv = __builtin_amdgcn_readfirstlane((int)(key & 63u));   // SGPR
    float d = __int_as_float(__builtin_amdgcn_readlane(__float_as_int(col[s]), piv));
    if (lane == s) pvec = piv;
    bool isPiv = (lane == piv);
    unsigned db = __float_as_uint(fabsf(d));
    if (db == 0u) psum = 0.f;                              // -> logf(0) = -inf
    esum += (int)((db >> 23) & 0xFFu) - 127;
    psum *= __uint_as_float((db & 0x007FFFFFu) | 0x3F800000u);
    signflips += (d < 0.f) ? 1 : 0;
    float rd = __builtin_amdgcn_rcpf(d);
    float f = (elim || isPiv || d == 0.f) ? 0.f : col[s] * rd;
    if (isPiv) elim = true;
    #pragma unroll
    for (int j = s + 1; j < 64; ++j) {
      float uj = __int_as_float(__builtin_amdgcn_readlane(__float_as_int(col[j]), piv));
      col[j] = fmaf(-f, uj, col[j]);
    }
  }
  float logacc = logf(psum) + (float)esum * 0.6931471805599453f;
  int inv = 0;
  #pragma unroll
  for (int dd = 1; dd < 64; ++dd) {
    int other = __shfl_down(pvec, dd, 64);
    unsigned long long mm = __ballot((lane + dd < 64) && (pvec > other));
    if (lane == 0) inv += __popcll(mm);
  }
  if (lane == 0) {
    laS[k] = logacc;
    sgS[k] = (((inv + signflips) & 1)) ? -1.f : 1.f;
  }
  __syncthreads();
  if (threadIdx.x == 0) {
    float t0 = laS[0] + lc[0], t1 = laS[1] + lc[1];
    float t2 = laS[2] + lc[2], t3 = laS[3] + lc[3];
    float m = fmaxf(fmaxf(t0, t1), fmaxf(t2, t3));
    float S = sgS[0]*expf(t0-m) + sgS[1]*expf(t1-m) + sgS[2]*expf(t2-m) + sgS[3]*expf(t3-m);
    float re = logf(fabsf(S)) + m;
    float im = (S < 0.f) ? -3.14159265358979f : 0.f;   // planar [re|im]
    if (b      < out_size) out[b]      = re;
    if (BB + b < out_size) out[BB + b] = im;
  }
}

// ---------------- K4 fallback: monolithic (if ws too small) ------------------
__launch_bounds__(256)
__global__ void k4_det(const float* __restrict__ featP, const int* __restrict__ R,
                       const float* __restrict__ Wproj, const float* __restrict__ bproj,
                       float* __restrict__ la, float* __restrict__ sg) {
  int b = blockIdx.x, k = blockIdx.y;
  int tid = threadIdx.x;
  __shared__ float A[64][65];
  __shared__ float fL[64];
  __shared__ int Rl[64];
  if (tid < 64) {
    int base = (b*KKK + k)*256;
    fL[tid] = (featP[base + tid] + featP[base + 64 + tid] +
               featP[base + 128 + tid] + featP[base + 192 + tid]) * (1.f/512.f);
    Rl[tid] = R[b*NFF + tid];
  }
  __syncthreads();
  int j = tid & 63, ig = tid >> 6;
  for (int i = ig; i < 64; i += 4) {
    int col = Rl[i]*NFF + j;
    float acc = bproj[k*(NSITES*NFF) + col];
    const float* wp = Wproj + (size_t)(k*WDD)*32768 + col;
    #pragma unroll 4
    for (int o = 0; o < 64; ++o) acc += fL[o] * wp[(size_t)o * 32768];
    A[i][j] = acc;
  }
  __syncthreads();
  int t = tid & 63;
  int parity = 0;
  for (int s = 0; s < 64; ++s) {
    float v = (t >= s) ? fabsf(A[t][s]) : -1.f;
    int idx = t;
    #pragma unroll
    for (int m = 1; m < 64; m <<= 1) {
      float ov = __shfl_xor(v, m, 64);
      int oi = __shfl_xor(idx, m, 64);
      if (ov > v || (ov == v && oi < idx)) { v = ov; idx = oi; }
    }
    int piv = idx;
    __syncthreads();
    if (piv != s) {
      if (t < 16) {
        int j2 = ig*16 + t;
        float tmp = A[s][j2]; A[s][j2] = A[piv][j2]; A[piv][j2] = tmp;
      }
      parity ^= 1;
    }
    __syncthreads();
    float d = A[s][s];
    if (d != 0.f && t > s) {
      float f = A[t][s] / d;
      #pragma unroll
      for (int jj = 0; jj < 16; ++jj) {
        int j2 = ig*16 + jj;
        if (j2 > s) A[t][j2] -= f * A[s][j2];
      }
    }
    __syncthreads();
  }
  if (ig == 0) {
    float d = A[t][t];
    float l = logf(fabsf(d));
    #pragma unroll
    for (int m = 1; m < 64; m <<= 1) l += __shfl_xor(l, m, 64);
    unsigned long long neg = __ballot(d < 0.f);
    if (t == 0) {
      la[b*KKK + k] = l;
      int p = ((int)__popcll(neg) + parity) & 1;
      sg[b*KKK + k] = p ? -1.f : 1.f;
    }
  }
}

// ---------------- K5: signed complex logsumexp (fallback path only) ----------
__global__ void k5_out(const float* __restrict__ la, const float* __restrict__ sg,
                       const float* __restrict__ lc, float* __restrict__ out, int out_size) {
  int b = blockIdx.x * blockDim.x + threadIdx.x;
  if (b >= BB) return;
  float t0 = la[b*KKK+0] + lc[0];
  float t1 = la[b*KKK+1] + lc[1];
  float t2 = la[b*KKK+2] + lc[2];
  float t3 = la[b*KKK+3] + lc[3];
  float m = fmaxf(fmaxf(t0, t1), fmaxf(t2, t3));
  float S = sg[b*KKK+0]*expf(t0-m) + sg[b*KKK+1]*expf(t1-m)
          + sg[b*KKK+2]*expf(t2-m) + sg[b*KKK+3]*expf(t3-m);
  float re = logf(fabsf(S)) + m;
  float im = (S < 0.f) ? -3.14159265358979f : 0.f;
  if (b      < out_size) out[b]      = re;
  if (BB + b < out_size) out[BB + b] = im;
}

extern "C" void kernel_launch(void* const* d_in, const int* in_sizes, int n_in,
                              void* d_out, int out_size, void* d_ws, size_t ws_size,
                              hipStream_t stream) {
  const int*   n        = (const int*)  d_in[0];
  const float* W_lift   = (const float*)d_in[1];
  const float* b_lift   = (const float*)d_in[2];
  const float* Wsp_re   = (const float*)d_in[3];
  const float* Wsp_im   = (const float*)d_in[4];
  const float* W_pt     = (const float*)d_in[5];
  const float* b_pt     = (const float*)d_in[6];
  const float* W_proj   = (const float*)d_in[7];
  const float* b_proj   = (const float*)d_in[8];
  const float* log_c    = (const float*)d_in[9];

  char* ws = (char*)d_ws;
  int*   R      = (int*)  (ws + OFF_R);
  float* Nf     = (float*)(ws + OFF_NF);
  float2* WLc   = (float2*)(ws + OFF_WLC);
  float* PT     = (float*)(ws + OFF_PT);
  float* C0     = (float*)(ws + OFF_C0);
  float* featP  = (float*)(ws + OFF_FEATP);
  float* la     = (float*)(ws + OFF_LA);
  float* sg     = (float*)(ws + OFF_SG);
  float* featC  = (float*)(ws + OFF_FEATC);
  int*   scnt   = (int*)  (ws + OFF_CNT);
  int*   lists  = (int*)  (ws + OFF_LISTS);
  float* Astore = (float*)(ws + OFF_ASTORE);

  k0_prep<<<dim3(256), dim3(256), 0, stream>>>(W_lift, b_lift, Wsp_re, Wsp_im, W_pt, b_pt,
                                               WLc, PT, C0, scnt);
  k1_occ<<<dim3(BB), dim3(NSITES), 0, stream>>>(n, R, scnt, lists);
  k2_nf<<<dim3(BB), dim3(256), 0, stream>>>(R, Nf);
  k3_field<<<dim3(BB, KKK, 4), dim3(256), 0, stream>>>(n, Nf, WLc, PT, C0, featP);
  if (ws_size >= (size_t)WS_NEED) {
    kf_comb<<<dim3(BB), dim3(256), 0, stream>>>(featP, featC);
    k4a_proj<<<dim3(NSITES, KKK), dim3(256), 0, stream>>>(featC, scnt, lists, W_proj, b_proj, Astore);
    k4b_lu<<<dim3(BB), dim3(256), 0, stream>>>(Astore, log_c, (float*)d_out, out_size);
  } else {
    k4_det<<<dim3(BB, KKK), dim3(256), 0, stream>>>(featP, R, W_proj, b_proj, la, sg);
    k5_out<<<dim3(4), dim3(256), 0, stream>>>(la, sg, log_c, (float*)d_out, out_size);
  }
}